// Round 17
// baseline (26600.507 us; speedup 1.0000x reference)
//
#include <hip/hip_runtime.h>
#include <hip/hip_fp16.h>
#include <stdint.h>

#define SEQ_LEN 16384
#define H       512
#define NWG     32      // WG k owns h[16k..16k+16)
#define HK      16
#define T       512
#define NR      48      // rows per matrix per WG (3 gates x 16)
#define WPITCH  257     // uint32 pitch per weight row (256 data + 1 pad)
// replica stride in u32: one replica = 2 parities x 512 words = 4KB
#define REPW    1024

typedef unsigned long long u64;
typedef _Float16 h2 __attribute__((ext_vector_type(2)));
typedef unsigned int u32x4 __attribute__((ext_vector_type(4)));

#define LD_AG(p)   __hip_atomic_load((p),      __ATOMIC_RELAXED, __HIP_MEMORY_SCOPE_AGENT)
#define ST_AG(p,v) __hip_atomic_store((p),(v), __ATOMIC_RELAXED, __HIP_MEMORY_SCOPE_AGENT)

__device__ __forceinline__ h2 as_h2(uint32_t u) {
    union { uint32_t u; h2 h; } c; c.u = u; return c.h;
}

#if defined(__has_builtin)
#if __has_builtin(__builtin_amdgcn_fdot2)
#define FDOT2(a, b, c) __builtin_amdgcn_fdot2((a), (b), (c), false)
#endif
#endif
#ifndef FDOT2
__device__ __forceinline__ float fdot2_sw(h2 a, h2 b, float c) {
    return fmaf((float)a.x, (float)b.x, fmaf((float)a.y, (float)b.y, c));
}
#define FDOT2(a, b, c) fdot2_sw((a), (b), (c))
#endif

__device__ __forceinline__ uint32_t pk2(float a, float b) {
    return (uint32_t)__half_as_ushort(__float2half(a)) |
           ((uint32_t)__half_as_ushort(__float2half(b)) << 16);
}

// champion 16B poll: one dwordx4, L1/L2-bypassed, dependent spin (PROVEN)
__device__ __forceinline__ u32x4 poll16(const uint32_t* p) {
    u32x4 v;
    asm volatile("global_load_dwordx4 %0, %1, off sc0 sc1\n\t"
                 "s_waitcnt vmcnt(0)"
                 : "=v"(v) : "v"(p) : "memory");
    return v;
}

// exchange word: [f16 value (hi 16) | step tag (lo 16)]; R replicas of the
// 2-parity buffer. Init all replicas (replay-safe).
__global__ void gru_init(uint32_t* __restrict__ tag32, int R) {
    int i = blockIdx.x * blockDim.x + threadIdx.x;
    if (i < R * REPW) {
        int w = i & (REPW - 1);
        ST_AG(&tag32[i], (w < H) ? 0u : 0xFFFFu);   // par0: h0=0 tag0; par1: invalid
    }
}

__launch_bounds__(T, 1)
__global__ void gru_main(const float* __restrict__ x,
                         const float* __restrict__ Wih,
                         const float* __restrict__ Whh,
                         const float* __restrict__ bih,
                         const float* __restrict__ bhh,
                         float* __restrict__ out,
                         uint32_t* __restrict__ tag32,
                         int R)
{
    const int wg  = blockIdx.x;
    const int tid = threadIdx.x;
    const int j0  = wg * HK;
    // this WG's read replica (round-robin across WGs)
    uint32_t* const myrep = tag32 + (size_t)(wg & (R - 1)) * REPW;

    __shared__ uint32_t w_lds[2 * NR * WPITCH];  // rows 0..47 W_ih, 48..95 W_hh (f16 pairs)
    __shared__ uint32_t x_u[2][H / 2];           // packed f16x2 x
    __shared__ uint32_t h_u[2][H / 2];           // packed f16x2 h
    __shared__ float    sums_g[2][NR];
    __shared__ float    sums_h[2][NR];
    __shared__ float    bsum_g[NR];
    __shared__ float    bsum_h[NR];

    __half* wh = (__half*)w_lds;                 // half pitch = 2*WPITCH

    // ---- prologue: stage weights f32 -> f16 LDS ----
    for (int idx = tid; idx < 2 * NR * H; idx += T) {
        int r  = idx >> 9;                       // 0..95
        int k  = idx & (H - 1);
        int rr = (r < NR) ? r : r - NR;
        int g  = rr >> 4;
        int jj = rr & 15;
        int grow = g * H + j0 + jj;
        float w = (r < NR) ? Wih[(size_t)grow * H + k] : Whh[(size_t)grow * H + k];
        wh[r * (2 * WPITCH) + k] = __float2half(w);
    }
    if (tid < NR) {
        int g  = tid >> 4;
        int jj = tid & 15;
        int grow = g * H + j0 + jj;
        bsum_g[tid] = (g == 2) ? bih[grow] : (bih[grow] + bhh[grow]);
        bsum_h[tid] = (g == 2) ? bhh[grow] : 0.0f;
    }
    if (tid < 128) {                             // prefill x_0 (packed f16)
        float4 x0 = ((const float4*)x)[tid];
        ((uint2*)x_u[0])[tid] = make_uint2(pk2(x0.x, x0.y), pk2(x0.z, x0.w));
    }
    __syncthreads();

    // dot-thread mapping (waves 2..7): row 0..47, chunk 0..7
    const int idxd = tid - 128;
    const int row  = idxd >> 3;                  // 0..47
    const int c8   = idxd & 7;                   // == tid&7

    // ---- W_hh into registers, pre-staggered so loop indices are static ----
    uint32_t wreg[32];
    if (tid >= 128) {
        const uint32_t* wr = w_lds + (NR + row) * WPITCH + c8 * 32;
        #pragma unroll
        for (int i = 0; i < 32; ++i) wreg[i] = wr[(i + 4 * c8) & 31];
    }
    __syncthreads();

    float4 xp;
    if (tid < 128) xp = ((const float4*)(x + H))[tid];   // x_1
    float hprev = 0.0f;                          // own h (wave-2 lanes 0..15)

    for (int t = 0; t < SEQ_LEN; ++t) {
        const int par = t & 1, nxt = par ^ 1;

        if (tid < 128) {
            // issue x_{t+2} prefetch (hidden under the spin)
            int tq = t + 2; if (tq >= SEQ_LEN) tq = SEQ_LEN - 1;
            float4 xq = ((const float4*)(x + (size_t)tq * H))[tid];

            // ---- champion tight dependent spin on 4 tagged words (my replica) ----
            const uint32_t need = (uint32_t)t & 0xFFFFu;
            const uint32_t* base = myrep + (size_t)par * H + 4 * tid;
            u32x4 v = poll16(base);
            while ((((v[0] ^ need) | (v[1] ^ need)) |
                    ((v[2] ^ need) | (v[3] ^ need))) & 0xFFFFu)
                v = poll16(base);
            // strip tags -> packed f16 pairs (pure bit ops)
            uint32_t p0 = (v[0] >> 16) | (v[1] & 0xFFFF0000u);
            uint32_t p1 = (v[2] >> 16) | (v[3] & 0xFFFF0000u);
            ((uint2*)h_u[par])[tid] = make_uint2(p0, p1);

            __syncthreads();   // A: h_u[par] + sums_g[par] ready
            // commit x_{t+1} as packed f16 (off critical path for dotters)
            ((uint2*)x_u[nxt])[tid] = make_uint2(pk2(xp.x, xp.y), pk2(xp.z, xp.w));
            xp = xq;
            __syncthreads();   // B: sums_h[par] + x_u[nxt] ready
            // pollers immediately proceed to next step's spin
        } else {
            // ---- gi dots over x_u[par] (weights from LDS, fdot2) ----
            {
                const uint32_t* gw = w_lds + row * WPITCH + c8 * 32;
                const uint32_t* B  = &x_u[par][c8 * 32];
                float acc = 0.0f;
                #pragma unroll
                for (int i = 0; i < 32; ++i) {
                    int s = (i + 4 * c8) & 31;
                    acc = FDOT2(as_h2(gw[s]), as_h2(B[s]), acc);
                }
                acc += __shfl_xor(acc, 1);
                acc += __shfl_xor(acc, 2);
                acc += __shfl_xor(acc, 4);
                if (c8 == 0) sums_g[par][row] = acc + bsum_g[row];
            }
            __syncthreads();   // A

            // ---- hh dots over h_u[par] (weights from registers, fdot2) ----
            {
                const uint32_t* B = &h_u[par][c8 * 32];
                float acc = 0.0f;
                #pragma unroll
                for (int i = 0; i < 32; ++i) {
                    int s = (i + 4 * c8) & 31;
                    acc = FDOT2(as_h2(wreg[i]), as_h2(B[s]), acc);
                }
                acc += __shfl_xor(acc, 1);
                acc += __shfl_xor(acc, 2);
                acc += __shfl_xor(acc, 4);
                if (c8 == 0) sums_h[par][row] = acc + bsum_h[row];
            }
            __syncthreads();   // B

            // ---- gates + publish: wave 2, lanes 0..15; direct u32 stores x R replicas ----
            if (tid < 192) {
                int j = tid & 63;
                if (j < 16) {
                    float sg0 = sums_g[par][j],      sg1 = sums_g[par][16 + j], sg2 = sums_g[par][32 + j];
                    float sh0 = sums_h[par][j],      sh1 = sums_h[par][16 + j], sh2 = sums_h[par][32 + j];
                    float r_ = 1.0f / (1.0f + __expf(-(sg0 + sh0)));
                    float z_ = 1.0f / (1.0f + __expf(-(sg1 + sh1)));
                    float a  = sg2 + r_ * sh2;
                    a = fminf(12.0f, fmaxf(-12.0f, a));
                    float e2 = __expf(2.0f * a);
                    float n_ = (e2 - 1.0f) / (e2 + 1.0f);
                    float hnew = (1.0f - z_) * n_ + z_ * hprev;
                    hprev = hnew;
                    uint32_t pk = ((uint32_t)__half_as_ushort(__float2half(hnew)) << 16)
                                | ((uint32_t)(t + 1) & 0xFFFFu);
                    // fire-and-forget: one coalesced 64B write per replica
                    uint32_t* pb = tag32 + (size_t)nxt * H + j0 + j;
                    for (int r = 0; r < R; ++r)
                        ST_AG(pb + (size_t)r * REPW, pk);
                    out[(size_t)t * H + j0 + j] = hnew;   // off critical path
                }
            }
            // wave 2 proceeds to next step's gi (lateness absorbed at barrier A)
        }
    }
}

extern "C" void kernel_launch(void* const* d_in, const int* in_sizes, int n_in,
                              void* d_out, int out_size, void* d_ws, size_t ws_size,
                              hipStream_t stream) {
    const float* x   = (const float*)d_in[0];
    const float* Wih = (const float*)d_in[1];
    const float* Whh = (const float*)d_in[2];
    const float* bih = (const float*)d_in[3];
    const float* bhh = (const float*)d_in[4];
    float* out = (float*)d_out;
    uint32_t* tag32 = (uint32_t*)d_ws;

    // replicas (power of 2): 8 needs 32KB, 4 needs 16KB, else champion layout
    int R = (ws_size >= 8 * REPW * 4) ? 8 : ((ws_size >= 4 * REPW * 4) ? 4 : 1);

    gru_init<<<16, 512, 0, stream>>>(tag32, R);
    gru_main<<<NWG, T, 0, stream>>>(x, Wih, Whh, bih, bhh, out, tag32, R);
}

// Round 18
// 23333.952 us; speedup vs baseline: 1.1400x; 1.1400x over previous
//
#include <hip/hip_runtime.h>
#include <hip/hip_fp16.h>
#include <stdint.h>

#define SEQ_LEN 16384
#define H       512
#define NWG     32      // WG k owns h[16k..16k+16)
#define HK      16
#define T       512
#define NR      48      // rows per matrix per WG (3 gates x 16)
#define WPITCH  257     // uint32 pitch per weight row (256 data + 1 pad)

typedef unsigned long long u64;
typedef _Float16 h2 __attribute__((ext_vector_type(2)));
typedef unsigned int u32x4 __attribute__((ext_vector_type(4)));

#define LD_AG(p)   __hip_atomic_load((p),      __ATOMIC_RELAXED, __HIP_MEMORY_SCOPE_AGENT)
#define ST_AG(p,v) __hip_atomic_store((p),(v), __ATOMIC_RELAXED, __HIP_MEMORY_SCOPE_AGENT)

__device__ __forceinline__ h2 as_h2(uint32_t u) {
    union { uint32_t u; h2 h; } c; c.u = u; return c.h;
}

#if defined(__has_builtin)
#if __has_builtin(__builtin_amdgcn_fdot2)
#define FDOT2(a, b, c) __builtin_amdgcn_fdot2((a), (b), (c), false)
#endif
#endif
#ifndef FDOT2
__device__ __forceinline__ float fdot2_sw(h2 a, h2 b, float c) {
    return fmaf((float)a.x, (float)b.x, fmaf((float)a.y, (float)b.y, c));
}
#define FDOT2(a, b, c) fdot2_sw((a), (b), (c))
#endif

__device__ __forceinline__ uint32_t pk2(float a, float b) {
    return (uint32_t)__half_as_ushort(__float2half(a)) |
           ((uint32_t)__half_as_ushort(__float2half(b)) << 16);
}

// champion 16B poll: one dwordx4, L1/L2-bypassed, dependent spin (PROVEN)
__device__ __forceinline__ u32x4 poll16(const uint32_t* p) {
    u32x4 v;
    asm volatile("global_load_dwordx4 %0, %1, off sc0 sc1\n\t"
                 "s_waitcnt vmcnt(0)"
                 : "=v"(v) : "v"(p) : "memory");
    return v;
}

// exchange word: [f16 value (hi 16) | step tag (lo 16)]
__global__ void gru_init(uint32_t* __restrict__ tag32) {
    int i = blockIdx.x * blockDim.x + threadIdx.x;
    if (i < H)            ST_AG(&tag32[i], 0u);        // h0 = 0, tag 0
    else if (i < 2 * H)   ST_AG(&tag32[i], 0xFFFFu);   // invalid tag
}

__launch_bounds__(T, 1)
__global__ void gru_main(const float* __restrict__ x,
                         const float* __restrict__ Wih,
                         const float* __restrict__ Whh,
                         const float* __restrict__ bih,
                         const float* __restrict__ bhh,
                         float* __restrict__ out,
                         uint32_t* __restrict__ tag32)
{
    const int wg  = blockIdx.x;
    const int tid = threadIdx.x;
    const int j0  = wg * HK;

    __shared__ uint32_t w_lds[2 * NR * WPITCH];  // rows 0..47 W_ih, 48..95 W_hh (f16 pairs)
    __shared__ uint32_t x_u[2][H / 2];           // packed f16x2 x
    __shared__ __align__(16) uint32_t h_u[2][H / 2];   // packed f16x2 h (16B-aligned for b128)
    __shared__ float    sums_g[2][NR];
    __shared__ float    sums_h[2][NR];
    __shared__ float    bsum_g[NR];
    __shared__ float    bsum_h[NR];

    __half* wh = (__half*)w_lds;                 // half pitch = 2*WPITCH

    // ---- prologue: stage weights f32 -> f16 LDS ----
    for (int idx = tid; idx < 2 * NR * H; idx += T) {
        int r  = idx >> 9;                       // 0..95
        int k  = idx & (H - 1);
        int rr = (r < NR) ? r : r - NR;
        int g  = rr >> 4;
        int jj = rr & 15;
        int grow = g * H + j0 + jj;
        float w = (r < NR) ? Wih[(size_t)grow * H + k] : Whh[(size_t)grow * H + k];
        wh[r * (2 * WPITCH) + k] = __float2half(w);
    }
    if (tid < NR) {
        int g  = tid >> 4;
        int jj = tid & 15;
        int grow = g * H + j0 + jj;
        bsum_g[tid] = (g == 2) ? bih[grow] : (bih[grow] + bhh[grow]);
        bsum_h[tid] = (g == 2) ? bhh[grow] : 0.0f;
    }
    if (tid < 128) {                             // prefill x_0 (packed f16)
        float4 x0 = ((const float4*)x)[tid];
        ((uint2*)x_u[0])[tid] = make_uint2(pk2(x0.x, x0.y), pk2(x0.z, x0.w));
    }
    __syncthreads();

    // dot-thread mapping (waves 2..7): row 0..47, chunk 0..7
    const int idxd = tid - 128;
    const int row  = idxd >> 3;                  // 0..47
    const int c8   = idxd & 7;                   // == tid&7

    // ---- W_hh into registers, pre-staggered so loop indices are static ----
    // wreg[4j+k] pairs with h-word 4*((j+c8)&7)+k of chunk c8 (b128 rotation)
    uint32_t wreg[32];
    if (tid >= 128) {
        const uint32_t* wr = w_lds + (NR + row) * WPITCH + c8 * 32;
        #pragma unroll
        for (int i = 0; i < 32; ++i) wreg[i] = wr[(i + 4 * c8) & 31];
    }
    __syncthreads();

    float4 xp;
    if (tid < 128) xp = ((const float4*)(x + H))[tid];   // x_1
    float hprev = 0.0f;                          // own h (wave-2 lanes 0..15)

    for (int t = 0; t < SEQ_LEN; ++t) {
        const int par = t & 1, nxt = par ^ 1;

        if (tid < 128) {
            // issue x_{t+2} prefetch (hidden under the spin)
            int tq = t + 2; if (tq >= SEQ_LEN) tq = SEQ_LEN - 1;
            float4 xq = ((const float4*)(x + (size_t)tq * H))[tid];

            // ---- champion tight dependent spin on 4 tagged words ----
            const uint32_t need = (uint32_t)t & 0xFFFFu;
            const uint32_t* base = tag32 + (size_t)par * H + 4 * tid;
            u32x4 v = poll16(base);
            while ((((v[0] ^ need) | (v[1] ^ need)) |
                    ((v[2] ^ need) | (v[3] ^ need))) & 0xFFFFu)
                v = poll16(base);
            // post-detect path is latency-critical -> brief priority boost
            __builtin_amdgcn_s_setprio(1);
            uint32_t p0 = (v[0] >> 16) | (v[1] & 0xFFFF0000u);
            uint32_t p1 = (v[2] >> 16) | (v[3] & 0xFFFF0000u);
            ((uint2*)h_u[par])[tid] = make_uint2(p0, p1);
            __builtin_amdgcn_s_setprio(0);

            __syncthreads();   // A: h_u[par] + sums_g[par] ready
            // commit x_{t+1} as packed f16 (off critical path for dotters)
            ((uint2*)x_u[nxt])[tid] = make_uint2(pk2(xp.x, xp.y), pk2(xp.z, xp.w));
            xp = xq;
            __syncthreads();   // B: sums_h[par] + x_u[nxt] ready
            // pollers immediately proceed to next step's spin
        } else {
            // ---- gi dots over x_u[par] (weights from LDS, fdot2) ----
            {
                const uint32_t* gw = w_lds + row * WPITCH + c8 * 32;
                const uint32_t* B  = &x_u[par][c8 * 32];
                float acc = 0.0f;
                #pragma unroll
                for (int i = 0; i < 32; ++i) {
                    int s = (i + 4 * c8) & 31;
                    acc = FDOT2(as_h2(gw[s]), as_h2(B[s]), acc);
                }
                acc += __shfl_xor(acc, 1);
                acc += __shfl_xor(acc, 2);
                acc += __shfl_xor(acc, 4);
                if (c8 == 0) sums_g[par][row] = acc + bsum_g[row];
            }
            __syncthreads();   // A

            // ---- hh dots: b128 LDS reads + 4 independent accumulators ----
            {
                const uint4* B4 = (const uint4*)&h_u[par][0];   // 64 uint4
                float a0 = 0.0f, a1 = 0.0f, a2 = 0.0f, a3 = 0.0f;
                #pragma unroll
                for (int j = 0; j < 8; ++j) {
                    uint4 b = B4[c8 * 8 + ((j + c8) & 7)];      // 16B, rotated
                    a0 = FDOT2(as_h2(wreg[4 * j]),     as_h2(b.x), a0);
                    a1 = FDOT2(as_h2(wreg[4 * j + 1]), as_h2(b.y), a1);
                    a2 = FDOT2(as_h2(wreg[4 * j + 2]), as_h2(b.z), a2);
                    a3 = FDOT2(as_h2(wreg[4 * j + 3]), as_h2(b.w), a3);
                }
                float acc = (a0 + a1) + (a2 + a3);
                acc += __shfl_xor(acc, 1);
                acc += __shfl_xor(acc, 2);
                acc += __shfl_xor(acc, 4);
                if (c8 == 0) sums_h[par][row] = acc + bsum_h[row];
            }
            __syncthreads();   // B

            // ---- gates + publish: wave 2, lanes 0..15; direct u32 stores ----
            if (tid < 192) {
                int j = tid & 63;
                if (j < 16) {
                    __builtin_amdgcn_s_setprio(1);   // beat gi-(t+1) issue pressure
                    float sg0 = sums_g[par][j],      sg1 = sums_g[par][16 + j], sg2 = sums_g[par][32 + j];
                    float sh0 = sums_h[par][j],      sh1 = sums_h[par][16 + j], sh2 = sums_h[par][32 + j];
                    float r_ = 1.0f / (1.0f + __expf(-(sg0 + sh0)));
                    float z_ = 1.0f / (1.0f + __expf(-(sg1 + sh1)));
                    float a  = sg2 + r_ * sh2;
                    a = fminf(12.0f, fmaxf(-12.0f, a));
                    float e2 = __expf(2.0f * a);
                    float n_ = (e2 - 1.0f) / (e2 + 1.0f);
                    float hnew = (1.0f - z_) * n_ + z_ * hprev;
                    hprev = hnew;
                    uint32_t pk = ((uint32_t)__half_as_ushort(__float2half(hnew)) << 16)
                                | ((uint32_t)(t + 1) & 0xFFFFu);
                    ST_AG(&tag32[(size_t)nxt * H + j0 + j], pk);
                    __builtin_amdgcn_s_setprio(0);
                    out[(size_t)t * H + j0 + j] = hnew;   // off critical path
                }
            }
            // wave 2 proceeds to next step's gi (lateness absorbed at barrier A)
        }
    }
}

extern "C" void kernel_launch(void* const* d_in, const int* in_sizes, int n_in,
                              void* d_out, int out_size, void* d_ws, size_t ws_size,
                              hipStream_t stream) {
    const float* x   = (const float*)d_in[0];
    const float* Wih = (const float*)d_in[1];
    const float* Whh = (const float*)d_in[2];
    const float* bih = (const float*)d_in[3];
    const float* bhh = (const float*)d_in[4];
    float* out = (float*)d_out;
    uint32_t* tag32 = (uint32_t*)d_ws;           // 4 KB exchange

    gru_init<<<2, 512, 0, stream>>>(tag32);
    gru_main<<<NWG, T, 0, stream>>>(x, Wih, Whh, bih, bhh, out, tag32);
}